// Round 1
// baseline (182.596 us; speedup 1.0000x reference)
//
#include <hip/hip_runtime.h>

typedef float f32x4 __attribute__((ext_vector_type(4)));
typedef short short8 __attribute__((ext_vector_type(8)));

#define DEVI static __device__ __forceinline__

DEVI ushort f2bf(float f) {
  unsigned u = __builtin_bit_cast(unsigned, f);
  u += 0x7fffu + ((u >> 16) & 1u);
  return (ushort)(u >> 16);
}

DEVI short8 pack8(float4 a, float4 b) {
  union { ushort u[8]; short8 v; } t;
  t.u[0] = f2bf(a.x); t.u[1] = f2bf(a.y); t.u[2] = f2bf(a.z); t.u[3] = f2bf(a.w);
  t.u[4] = f2bf(b.x); t.u[5] = f2bf(b.y); t.u[6] = f2bf(b.z); t.u[7] = f2bf(b.w);
  return t.v;
}

DEVI f32x4 MFMA16(short8 a, short8 b, f32x4 c) {
  return __builtin_amdgcn_mfma_f32_16x16x32_bf16(a, b, c, 0, 0, 0);
}

// ---------------- bias precompute: bias[h][208][208] ----------------
__global__ void prep_bias(const float* __restrict__ table, const int* __restrict__ rel_idx,
                          float* __restrict__ bias) {
  int i = blockIdx.x * 256 + threadIdx.x;
  if (i >= 12 * 208 * 208) return;
  int k = i % 208;
  int t = i / 208;
  int q = t % 208;
  int h = t / 208;
  float v;
  if (k >= 197) v = -1e30f;
  else if (q == 0 || k == 0 || q >= 197) v = 0.0f;
  else v = table[rel_idx[(q - 1) * 196 + (k - 1)] * 12 + h];
  bias[i] = v;
}

// ---------------- QKV GEMM: [12608,768] @ [2304,768]^T, scatter to q/k/v bf16 ----------------
__launch_bounds__(512)
__global__ void qkv_gemm(const float* __restrict__ X, const float* __restrict__ W,
                         ushort* __restrict__ qws, ushort* __restrict__ kws,
                         ushort* __restrict__ vws) {
  __shared__ __align__(16) ushort As[128 * 72];
  __shared__ __align__(16) ushort Bs[128 * 72];
  const int tid = threadIdx.x;
  const int lane = tid & 63, wid = tid >> 6;
  const int wm = wid >> 2, wn = wid & 3;
  const int l15 = lane & 15, l4 = lane >> 4;
  const int bm = blockIdx.y, bn = blockIdx.x;

  const int srow = tid >> 2;
  const int scol = (tid & 3) << 4;
  long arow = (long)bm * 128 + srow; if (arow > 12607) arow = 12607;
  const float* ap = X + arow * 768 + scol;
  const float* bp = W + ((long)bn * 128 + srow) * 768 + scol;
  ushort* asw = &As[srow * 72 + scol];
  ushort* bsw = &Bs[srow * 72 + scol];

  f32x4 acc[4][2];
#pragma unroll
  for (int m = 0; m < 4; m++)
#pragma unroll
    for (int n = 0; n < 2; n++) acc[m][n] = (f32x4)0.0f;

  for (int k0 = 0; k0 < 768; k0 += 64) {
    float4 av0 = *(const float4*)(ap + k0);
    float4 av1 = *(const float4*)(ap + k0 + 4);
    float4 av2 = *(const float4*)(ap + k0 + 8);
    float4 av3 = *(const float4*)(ap + k0 + 12);
    float4 bv0 = *(const float4*)(bp + k0);
    float4 bv1 = *(const float4*)(bp + k0 + 4);
    float4 bv2 = *(const float4*)(bp + k0 + 8);
    float4 bv3 = *(const float4*)(bp + k0 + 12);
    __syncthreads();
    *(short8*)(asw)     = pack8(av0, av1);
    *(short8*)(asw + 8) = pack8(av2, av3);
    *(short8*)(bsw)     = pack8(bv0, bv1);
    *(short8*)(bsw + 8) = pack8(bv2, bv3);
    __syncthreads();
#pragma unroll
    for (int kk = 0; kk < 2; kk++) {
      short8 af[4], bfr[2];
#pragma unroll
      for (int m = 0; m < 4; m++)
        af[m] = *(const short8*)&As[(wm * 64 + m * 16 + l15) * 72 + kk * 32 + (l4 << 3)];
#pragma unroll
      for (int n = 0; n < 2; n++)
        bfr[n] = *(const short8*)&Bs[(wn * 32 + n * 16 + l15) * 72 + kk * 32 + (l4 << 3)];
#pragma unroll
      for (int m = 0; m < 4; m++)
#pragma unroll
        for (int n = 0; n < 2; n++)
          acc[m][n] = MFMA16(af[m], bfr[n], acc[m][n]);
    }
  }

  // epilogue: decode (b, nseq, s, h, d); s uniform per block since 128*6 == 768
  const int s = bn / 6;
  ushort* dst = (s == 0) ? qws : ((s == 1) ? kws : vws);
  const float qscale = (s == 0) ? 0.125f : 1.0f;
#pragma unroll
  for (int m = 0; m < 4; m++) {
#pragma unroll
    for (int r = 0; r < 4; r++) {
      long gm = (long)bm * 128 + wm * 64 + m * 16 + l4 * 4 + r;
      if (gm >= 12608) continue;
      int b = (int)(gm / 197);
      int nseq = (int)(gm - (long)b * 197);
#pragma unroll
      for (int n = 0; n < 2; n++) {
        int gn = bn * 128 + wn * 32 + n * 16 + l15;
        int rem = gn - s * 768;
        int hh = rem >> 6, d = rem & 63;
        float v = acc[m][n][r] * qscale;
        dst[(size_t)((b * 12 + hh) * 197 + nseq) * 64 + d] = f2bf(v);
      }
    }
  }
}

// ---------------- fused attention per (b,h) ----------------
__launch_bounds__(512)
__global__ void attn(const ushort* __restrict__ qws, const ushort* __restrict__ kws,
                     const ushort* __restrict__ vws, const float* __restrict__ biasws,
                     ushort* __restrict__ aout) {
  __shared__ __align__(16) ushort Ks[208 * 72];
  __shared__ __align__(16) ushort Vt[64 * 232];
  __shared__ __align__(16) ushort Ps[8 * 16 * 232];

  const int bh = blockIdx.x;
  const int b = bh / 12;
  const int h = bh - b * 12;
  const ushort* qb = qws + (size_t)bh * 197 * 64;
  const ushort* kb = kws + (size_t)bh * 197 * 64;
  const ushort* vb = vws + (size_t)bh * 197 * 64;

  const int tid = threadIdx.x;
  const int lane = tid & 63, wid = tid >> 6;
  const int l15 = lane & 15, l4 = lane >> 4;

  // stage K: 208 rows x 64 cols (zeros for rows >=197), row pad 72
  for (int c = tid; c < 208 * 8; c += 512) {
    int n = c >> 3, col = (c & 7) << 3;
    short8 v = (short8)0;
    if (n < 197) v = *(const short8*)(kb + n * 64 + col);
    *(short8*)&Ks[n * 72 + col] = v;
  }
  // stage V transposed: Vt[d][n], n in [0,224), row pad 232
  for (int c = tid; c < 224 * 8; c += 512) {
    int n = c % 224;
    int d0 = (c / 224) << 3;
    ushort tmp[8] = {0, 0, 0, 0, 0, 0, 0, 0};
    if (n < 197) {
      short8 v = *(const short8*)(vb + n * 64 + d0);
#pragma unroll
      for (int j = 0; j < 8; j++) tmp[j] = (ushort)v[j];
    }
#pragma unroll
    for (int j = 0; j < 8; j++) Vt[(d0 + j) * 232 + n] = tmp[j];
  }
  __syncthreads();

  ushort* pb = &Ps[wid * (16 * 232)];
  const float* biasb = biasws + (size_t)h * 208 * 208;

  for (int t = wid; t < 13; t += 8) {
    const int q0 = t * 16;
    int qr = q0 + l15; if (qr > 196) qr = 196;
    short8 aq0 = *(const short8*)(qb + qr * 64 + (l4 << 3));
    short8 aq1 = *(const short8*)(qb + qr * 64 + 32 + (l4 << 3));

    f32x4 sc[13];
#pragma unroll
    for (int ct = 0; ct < 13; ct++) {
      short8 b0 = *(const short8*)&Ks[(ct * 16 + l15) * 72 + (l4 << 3)];
      short8 b1 = *(const short8*)&Ks[(ct * 16 + l15) * 72 + 32 + (l4 << 3)];
      f32x4 s = (f32x4)0.0f;
      s = MFMA16(aq0, b0, s);
      s = MFMA16(aq1, b1, s);
      sc[ct] = s;
    }

    // bias + row max
    float mx[4] = {-1e38f, -1e38f, -1e38f, -1e38f};
#pragma unroll
    for (int ct = 0; ct < 13; ct++) {
#pragma unroll
      for (int r = 0; r < 4; r++) {
        float bv = biasb[(q0 + l4 * 4 + r) * 208 + ct * 16 + l15];
        float v = sc[ct][r] + bv;
        sc[ct][r] = v;
        mx[r] = fmaxf(mx[r], v);
      }
    }
#pragma unroll
    for (int r = 0; r < 4; r++) {
      mx[r] = fmaxf(mx[r], __shfl_xor(mx[r], 1));
      mx[r] = fmaxf(mx[r], __shfl_xor(mx[r], 2));
      mx[r] = fmaxf(mx[r], __shfl_xor(mx[r], 4));
      mx[r] = fmaxf(mx[r], __shfl_xor(mx[r], 8));
    }
    float sum[4] = {0.f, 0.f, 0.f, 0.f};
#pragma unroll
    for (int ct = 0; ct < 13; ct++) {
#pragma unroll
      for (int r = 0; r < 4; r++) {
        float p = __expf(sc[ct][r] - mx[r]);
        sc[ct][r] = p;
        sum[r] += p;
      }
    }
#pragma unroll
    for (int r = 0; r < 4; r++) {
      sum[r] += __shfl_xor(sum[r], 1);
      sum[r] += __shfl_xor(sum[r], 2);
      sum[r] += __shfl_xor(sum[r], 4);
      sum[r] += __shfl_xor(sum[r], 8);
    }

    // write P (bf16) to per-wave LDS, pad cols [208,224) with zeros
#pragma unroll
    for (int ct = 0; ct < 13; ct++)
#pragma unroll
      for (int r = 0; r < 4; r++)
        pb[(l4 * 4 + r) * 232 + ct * 16 + l15] = f2bf(sc[ct][r]);
#pragma unroll
    for (int r = 0; r < 4; r++)
      pb[(l4 * 4 + r) * 232 + 208 + l15] = 0;

    // PV: O[16,64] = P[16,224] @ V[224,64]
    short8 pa[7];
#pragma unroll
    for (int kk = 0; kk < 7; kk++)
      pa[kk] = *(const short8*)&pb[l15 * 232 + kk * 32 + (l4 << 3)];
    f32x4 o[4];
#pragma unroll
    for (int dt = 0; dt < 4; dt++) {
      f32x4 acc = (f32x4)0.0f;
#pragma unroll
      for (int kk = 0; kk < 7; kk++) {
        short8 bv = *(const short8*)&Vt[(dt * 16 + l15) * 232 + kk * 32 + (l4 << 3)];
        acc = MFMA16(pa[kk], bv, acc);
      }
      o[dt] = acc;
    }

    float rs[4];
#pragma unroll
    for (int r = 0; r < 4; r++) rs[r] = 1.0f / sum[r];
#pragma unroll
    for (int dt = 0; dt < 4; dt++) {
#pragma unroll
      for (int r = 0; r < 4; r++) {
        int row = q0 + l4 * 4 + r;
        if (row < 197) {
          float v = o[dt][r] * rs[r];
          aout[(size_t)(b * 197 + row) * 768 + h * 64 + dt * 16 + l15] = f2bf(v);
        }
      }
    }
  }
}

// ---------------- Proj GEMM: [12608,768](bf16) @ [768,768]^T + bias -> fp32 ----------------
__launch_bounds__(512)
__global__ void proj_gemm(const ushort* __restrict__ A, const float* __restrict__ W,
                          const float* __restrict__ bprj, float* __restrict__ out) {
  __shared__ __align__(16) ushort As[128 * 72];
  __shared__ __align__(16) ushort Bs[128 * 72];
  const int tid = threadIdx.x;
  const int lane = tid & 63, wid = tid >> 6;
  const int wm = wid >> 2, wn = wid & 3;
  const int l15 = lane & 15, l4 = lane >> 4;
  const int bm = blockIdx.y, bn = blockIdx.x;

  const int srow = tid >> 2;
  const int scol = (tid & 3) << 4;
  long arow = (long)bm * 128 + srow; if (arow > 12607) arow = 12607;
  const ushort* ap = A + arow * 768 + scol;
  const float* bp = W + ((long)bn * 128 + srow) * 768 + scol;
  ushort* asw = &As[srow * 72 + scol];
  ushort* bsw = &Bs[srow * 72 + scol];

  f32x4 acc[4][2];
#pragma unroll
  for (int m = 0; m < 4; m++)
#pragma unroll
    for (int n = 0; n < 2; n++) acc[m][n] = (f32x4)0.0f;

  for (int k0 = 0; k0 < 768; k0 += 64) {
    short8 a0 = *(const short8*)(ap + k0);
    short8 a1 = *(const short8*)(ap + k0 + 8);
    float4 bv0 = *(const float4*)(bp + k0);
    float4 bv1 = *(const float4*)(bp + k0 + 4);
    float4 bv2 = *(const float4*)(bp + k0 + 8);
    float4 bv3 = *(const float4*)(bp + k0 + 12);
    __syncthreads();
    *(short8*)(asw)     = a0;
    *(short8*)(asw + 8) = a1;
    *(short8*)(bsw)     = pack8(bv0, bv1);
    *(short8*)(bsw + 8) = pack8(bv2, bv3);
    __syncthreads();
#pragma unroll
    for (int kk = 0; kk < 2; kk++) {
      short8 af[4], bfr[2];
#pragma unroll
      for (int m = 0; m < 4; m++)
        af[m] = *(const short8*)&As[(wm * 64 + m * 16 + l15) * 72 + kk * 32 + (l4 << 3)];
#pragma unroll
      for (int n = 0; n < 2; n++)
        bfr[n] = *(const short8*)&Bs[(wn * 32 + n * 16 + l15) * 72 + kk * 32 + (l4 << 3)];
#pragma unroll
      for (int m = 0; m < 4; m++)
#pragma unroll
        for (int n = 0; n < 2; n++)
          acc[m][n] = MFMA16(af[m], bfr[n], acc[m][n]);
    }
  }

  float bb[2];
#pragma unroll
  for (int n = 0; n < 2; n++) bb[n] = bprj[bn * 128 + wn * 32 + n * 16 + l15];
#pragma unroll
  for (int m = 0; m < 4; m++) {
#pragma unroll
    for (int r = 0; r < 4; r++) {
      long gm = (long)bm * 128 + wm * 64 + m * 16 + l4 * 4 + r;
      if (gm >= 12608) continue;
#pragma unroll
      for (int n = 0; n < 2; n++) {
        int gn = bn * 128 + wn * 32 + n * 16 + l15;
        out[(size_t)gm * 768 + gn] = acc[m][n][r] + bb[n];
      }
    }
  }
}

extern "C" void kernel_launch(void* const* d_in, const int* in_sizes, int n_in,
                              void* d_out, int out_size, void* d_ws, size_t ws_size,
                              hipStream_t stream) {
  const float* x      = (const float*)d_in[0];
  const float* w_qkv  = (const float*)d_in[1];
  const float* w_proj = (const float*)d_in[2];
  const float* b_proj = (const float*)d_in[3];
  const float* rpb    = (const float*)d_in[4];
  const int*   relidx = (const int*)d_in[5];
  float* out = (float*)d_out;

  char* ws = (char*)d_ws;
  const size_t HEAD_BYTES = (size_t)64 * 12 * 197 * 64 * 2; // 19,365,888
  ushort* qws  = (ushort*)(ws);
  ushort* kws  = (ushort*)(ws + HEAD_BYTES);
  ushort* vws  = (ushort*)(ws + 2 * HEAD_BYTES);
  ushort* aout = (ushort*)(ws + 3 * HEAD_BYTES);
  float*  bias = (float*)(ws + 4 * HEAD_BYTES);  // 12*208*208*4 = 2,076,672 B

  hipLaunchKernelGGL(prep_bias, dim3((12 * 208 * 208 + 255) / 256), dim3(256), 0, stream,
                     rpb, relidx, bias);
  hipLaunchKernelGGL(qkv_gemm, dim3(18, 99), dim3(512), 0, stream, x, w_qkv, qws, kws, vws);
  hipLaunchKernelGGL(attn, dim3(768), dim3(512), 0, stream, qws, kws, vws, bias, aout);
  hipLaunchKernelGGL(proj_gemm, dim3(6, 99), dim3(512), 0, stream, aout, w_proj, b_proj, out);
}

// Round 2
// 181.693 us; speedup vs baseline: 1.0050x; 1.0050x over previous
//
#include <hip/hip_runtime.h>

typedef float f32x4 __attribute__((ext_vector_type(4)));
typedef short short8 __attribute__((ext_vector_type(8)));

#define DEVI static __device__ __forceinline__

DEVI ushort f2bf(float f) {
  unsigned u = __builtin_bit_cast(unsigned, f);
  u += 0x7fffu + ((u >> 16) & 1u);
  return (ushort)(u >> 16);
}

DEVI short8 pack8(float4 a, float4 b) {
  union { ushort u[8]; short8 v; } t;
  t.u[0] = f2bf(a.x); t.u[1] = f2bf(a.y); t.u[2] = f2bf(a.z); t.u[3] = f2bf(a.w);
  t.u[4] = f2bf(b.x); t.u[5] = f2bf(b.y); t.u[6] = f2bf(b.z); t.u[7] = f2bf(b.w);
  return t.v;
}

DEVI f32x4 MFMA16(short8 a, short8 b, f32x4 c) {
  return __builtin_amdgcn_mfma_f32_16x16x32_bf16(a, b, c, 0, 0, 0);
}

// async global->LDS DMA, 16B per lane; LDS dest must be wave-uniform base (+lane*16 by HW)
DEVI void gld16(const ushort* g, ushort* l) {
  __builtin_amdgcn_global_load_lds(
      (const __attribute__((address_space(1))) unsigned int*)g,
      (__attribute__((address_space(3))) unsigned int*)l, 16, 0, 0);
}

// ---------------- fp32 -> bf16 bulk convert (8 elems/thread) ----------------
__global__ void cvt_bf16(const float* __restrict__ s, ushort* __restrict__ d, int n8) {
  int i = blockIdx.x * 256 + threadIdx.x;
  if (i >= n8) return;
  float4 a = ((const float4*)s)[i * 2];
  float4 b = ((const float4*)s)[i * 2 + 1];
  ((short8*)d)[i] = pack8(a, b);
}

// ---------------- bias precompute: bias[h][208][208] ----------------
__global__ void prep_bias(const float* __restrict__ table, const int* __restrict__ rel_idx,
                          float* __restrict__ bias) {
  int i = blockIdx.x * 256 + threadIdx.x;
  if (i >= 12 * 208 * 208) return;
  int k = i % 208;
  int t = i / 208;
  int q = t % 208;
  int h = t / 208;
  float v;
  if (k >= 197) v = -1e30f;
  else if (q == 0 || k == 0 || q >= 197) v = 0.0f;
  else v = table[rel_idx[(q - 1) * 196 + (k - 1)] * 12 + h];
  bias[i] = v;
}

// ---------------- QKV GEMM (m97 structure): bf16 [12608,768] @ bf16 [2304,768]^T ----------------
__launch_bounds__(256)
__global__ void qkv_gemm(const ushort* __restrict__ X, const ushort* __restrict__ W,
                         ushort* __restrict__ qws, ushort* __restrict__ kws,
                         ushort* __restrict__ vws) {
  __shared__ __align__(16) ushort As[128 * 64];
  __shared__ __align__(16) ushort Bs[128 * 64];
  const int tid = threadIdx.x;
  const int lane = tid & 63, wid = tid >> 6;
  const int wm = wid >> 1, wn = wid & 1;
  const int l15 = lane & 15, l4 = lane >> 4;
  const int bm = blockIdx.y, bn = blockIdx.x;

  const ushort* ga[4];
  const ushort* gb[4];
  ushort* la[4];
  ushort* lb[4];
#pragma unroll
  for (int i = 0; i < 4; i++) {
    int c = i * 256 + wid * 64 + lane;
    int row = c >> 3, col = (c & 7) << 3;
    long gr = (long)bm * 128 + row; if (gr > 12607) gr = 12607;
    ga[i] = X + gr * 768 + col;
    gb[i] = W + ((long)bn * 128 + row) * 768 + col;
    la[i] = As + (size_t)(i * 256 + wid * 64) * 8;
    lb[i] = Bs + (size_t)(i * 256 + wid * 64) * 8;
  }

  f32x4 acc[4][4];
#pragma unroll
  for (int m = 0; m < 4; m++)
#pragma unroll
    for (int n = 0; n < 4; n++) acc[m][n] = (f32x4)0.0f;

  for (int k0 = 0; k0 < 768; k0 += 64) {
    __syncthreads();
#pragma unroll
    for (int i = 0; i < 4; i++) gld16(ga[i] + k0, la[i]);
#pragma unroll
    for (int i = 0; i < 4; i++) gld16(gb[i] + k0, lb[i]);
    __syncthreads();
#pragma unroll
    for (int kk = 0; kk < 2; kk++) {
      short8 af[4], bfv[4];
#pragma unroll
      for (int m = 0; m < 4; m++)
        af[m] = *(const short8*)&As[(wm * 64 + m * 16 + l15) * 64 + kk * 32 + (l4 << 3)];
#pragma unroll
      for (int n = 0; n < 4; n++)
        bfv[n] = *(const short8*)&Bs[(wn * 64 + n * 16 + l15) * 64 + kk * 32 + (l4 << 3)];
#pragma unroll
      for (int m = 0; m < 4; m++)
#pragma unroll
        for (int n = 0; n < 4; n++)
          acc[m][n] = MFMA16(af[m], bfv[n], acc[m][n]);
    }
  }

  // epilogue: s uniform per block (128*6 == 768)
  const int s = bn / 6;
  ushort* dst = (s == 0) ? qws : ((s == 1) ? kws : vws);
  const float qscale = (s == 0) ? 0.125f : 1.0f;
  const int cbase = bn * 128 + wn * 64 - s * 768;
#pragma unroll
  for (int m = 0; m < 4; m++) {
#pragma unroll
    for (int r = 0; r < 4; r++) {
      long gm = (long)bm * 128 + wm * 64 + m * 16 + l4 * 4 + r;
      if (gm >= 12608) continue;
      int b = (int)(gm / 197);
      int nseq = (int)(gm - (long)b * 197);
#pragma unroll
      for (int n = 0; n < 4; n++) {
        int gn = cbase + n * 16 + l15;
        int hh = gn >> 6, d = gn & 63;
        dst[(size_t)((b * 12 + hh) * 197 + nseq) * 64 + d] = f2bf(acc[m][n][r] * qscale);
      }
    }
  }
}

// ---------------- fused attention per (b,h) ----------------
__launch_bounds__(512)
__global__ void attn(const ushort* __restrict__ qws, const ushort* __restrict__ kws,
                     const ushort* __restrict__ vws, const float* __restrict__ biasws,
                     ushort* __restrict__ aout) {
  __shared__ __align__(16) ushort Ks[208 * 72];
  __shared__ __align__(16) ushort Vt[64 * 232];
  __shared__ __align__(16) ushort Ps[8 * 16 * 232];

  const int bh = blockIdx.x;
  const int b = bh / 12;
  const int h = bh - b * 12;
  const ushort* qb = qws + (size_t)bh * 197 * 64;
  const ushort* kb = kws + (size_t)bh * 197 * 64;
  const ushort* vb = vws + (size_t)bh * 197 * 64;

  const int tid = threadIdx.x;
  const int lane = tid & 63, wid = tid >> 6;
  const int l15 = lane & 15, l4 = lane >> 4;

  for (int c = tid; c < 208 * 8; c += 512) {
    int n = c >> 3, col = (c & 7) << 3;
    short8 v = (short8)0;
    if (n < 197) v = *(const short8*)(kb + n * 64 + col);
    *(short8*)&Ks[n * 72 + col] = v;
  }
  for (int c = tid; c < 224 * 8; c += 512) {
    int n = c % 224;
    int d0 = (c / 224) << 3;
    ushort tmp[8] = {0, 0, 0, 0, 0, 0, 0, 0};
    if (n < 197) {
      short8 v = *(const short8*)(vb + n * 64 + d0);
#pragma unroll
      for (int j = 0; j < 8; j++) tmp[j] = (ushort)v[j];
    }
#pragma unroll
    for (int j = 0; j < 8; j++) Vt[(d0 + j) * 232 + n] = tmp[j];
  }
  __syncthreads();

  ushort* pb = &Ps[wid * (16 * 232)];
  const float* biasb = biasws + (size_t)h * 208 * 208;

  for (int t = wid; t < 13; t += 8) {
    const int q0 = t * 16;
    int qr = q0 + l15; if (qr > 196) qr = 196;
    short8 aq0 = *(const short8*)(qb + qr * 64 + (l4 << 3));
    short8 aq1 = *(const short8*)(qb + qr * 64 + 32 + (l4 << 3));

    f32x4 sc[13];
#pragma unroll
    for (int ct = 0; ct < 13; ct++) {
      short8 b0 = *(const short8*)&Ks[(ct * 16 + l15) * 72 + (l4 << 3)];
      short8 b1 = *(const short8*)&Ks[(ct * 16 + l15) * 72 + 32 + (l4 << 3)];
      f32x4 s = (f32x4)0.0f;
      s = MFMA16(aq0, b0, s);
      s = MFMA16(aq1, b1, s);
      sc[ct] = s;
    }

    float mx[4] = {-1e38f, -1e38f, -1e38f, -1e38f};
#pragma unroll
    for (int ct = 0; ct < 13; ct++) {
#pragma unroll
      for (int r = 0; r < 4; r++) {
        float bv = biasb[(q0 + l4 * 4 + r) * 208 + ct * 16 + l15];
        float v = sc[ct][r] + bv;
        sc[ct][r] = v;
        mx[r] = fmaxf(mx[r], v);
      }
    }
#pragma unroll
    for (int r = 0; r < 4; r++) {
      mx[r] = fmaxf(mx[r], __shfl_xor(mx[r], 1));
      mx[r] = fmaxf(mx[r], __shfl_xor(mx[r], 2));
      mx[r] = fmaxf(mx[r], __shfl_xor(mx[r], 4));
      mx[r] = fmaxf(mx[r], __shfl_xor(mx[r], 8));
    }
    float sum[4] = {0.f, 0.f, 0.f, 0.f};
#pragma unroll
    for (int ct = 0; ct < 13; ct++) {
#pragma unroll
      for (int r = 0; r < 4; r++) {
        float p = __expf(sc[ct][r] - mx[r]);
        sc[ct][r] = p;
        sum[r] += p;
      }
    }
#pragma unroll
    for (int r = 0; r < 4; r++) {
      sum[r] += __shfl_xor(sum[r], 1);
      sum[r] += __shfl_xor(sum[r], 2);
      sum[r] += __shfl_xor(sum[r], 4);
      sum[r] += __shfl_xor(sum[r], 8);
    }

#pragma unroll
    for (int ct = 0; ct < 13; ct++)
#pragma unroll
      for (int r = 0; r < 4; r++)
        pb[(l4 * 4 + r) * 232 + ct * 16 + l15] = f2bf(sc[ct][r]);
#pragma unroll
    for (int r = 0; r < 4; r++)
      pb[(l4 * 4 + r) * 232 + 208 + l15] = 0;

    short8 pa[7];
#pragma unroll
    for (int kk = 0; kk < 7; kk++)
      pa[kk] = *(const short8*)&pb[l15 * 232 + kk * 32 + (l4 << 3)];
    f32x4 o[4];
#pragma unroll
    for (int dt = 0; dt < 4; dt++) {
      f32x4 acc = (f32x4)0.0f;
#pragma unroll
      for (int kk = 0; kk < 7; kk++) {
        short8 bv = *(const short8*)&Vt[(dt * 16 + l15) * 232 + kk * 32 + (l4 << 3)];
        acc = MFMA16(pa[kk], bv, acc);
      }
      o[dt] = acc;
    }

    float rs[4];
#pragma unroll
    for (int r = 0; r < 4; r++) rs[r] = 1.0f / sum[r];
#pragma unroll
    for (int dt = 0; dt < 4; dt++) {
#pragma unroll
      for (int r = 0; r < 4; r++) {
        int row = q0 + l4 * 4 + r;
        if (row < 197) {
          float v = o[dt][r] * rs[r];
          aout[(size_t)(b * 197 + row) * 768 + h * 64 + dt * 16 + l15] = f2bf(v);
        }
      }
    }
  }
}

// ---------------- Proj GEMM (m97 structure): bf16 [12608,768] @ bf16 [768,768]^T + bias -> fp32 ----------------
__launch_bounds__(256)
__global__ void proj_gemm(const ushort* __restrict__ A, const ushort* __restrict__ W,
                          const float* __restrict__ bprj, float* __restrict__ out) {
  __shared__ __align__(16) ushort As[128 * 64];
  __shared__ __align__(16) ushort Bs[128 * 64];
  const int tid = threadIdx.x;
  const int lane = tid & 63, wid = tid >> 6;
  const int wm = wid >> 1, wn = wid & 1;
  const int l15 = lane & 15, l4 = lane >> 4;
  const int bm = blockIdx.y, bn = blockIdx.x;

  const ushort* ga[4];
  const ushort* gb[4];
  ushort* la[4];
  ushort* lb[4];
#pragma unroll
  for (int i = 0; i < 4; i++) {
    int c = i * 256 + wid * 64 + lane;
    int row = c >> 3, col = (c & 7) << 3;
    long gr = (long)bm * 128 + row; if (gr > 12607) gr = 12607;
    ga[i] = A + gr * 768 + col;
    gb[i] = W + ((long)bn * 128 + row) * 768 + col;
    la[i] = As + (size_t)(i * 256 + wid * 64) * 8;
    lb[i] = Bs + (size_t)(i * 256 + wid * 64) * 8;
  }

  f32x4 acc[4][4];
#pragma unroll
  for (int m = 0; m < 4; m++)
#pragma unroll
    for (int n = 0; n < 4; n++) acc[m][n] = (f32x4)0.0f;

  for (int k0 = 0; k0 < 768; k0 += 64) {
    __syncthreads();
#pragma unroll
    for (int i = 0; i < 4; i++) gld16(ga[i] + k0, la[i]);
#pragma unroll
    for (int i = 0; i < 4; i++) gld16(gb[i] + k0, lb[i]);
    __syncthreads();
#pragma unroll
    for (int kk = 0; kk < 2; kk++) {
      short8 af[4], bfv[4];
#pragma unroll
      for (int m = 0; m < 4; m++)
        af[m] = *(const short8*)&As[(wm * 64 + m * 16 + l15) * 64 + kk * 32 + (l4 << 3)];
#pragma unroll
      for (int n = 0; n < 4; n++)
        bfv[n] = *(const short8*)&Bs[(wn * 64 + n * 16 + l15) * 64 + kk * 32 + (l4 << 3)];
#pragma unroll
      for (int m = 0; m < 4; m++)
#pragma unroll
        for (int n = 0; n < 4; n++)
          acc[m][n] = MFMA16(af[m], bfv[n], acc[m][n]);
    }
  }

  float bb[4];
#pragma unroll
  for (int n = 0; n < 4; n++) bb[n] = bprj[bn * 128 + wn * 64 + n * 16 + l15];
#pragma unroll
  for (int m = 0; m < 4; m++) {
#pragma unroll
    for (int r = 0; r < 4; r++) {
      long gm = (long)bm * 128 + wm * 64 + m * 16 + l4 * 4 + r;
      if (gm >= 12608) continue;
#pragma unroll
      for (int n = 0; n < 4; n++) {
        int gn = bn * 128 + wn * 64 + n * 16 + l15;
        out[(size_t)gm * 768 + gn] = acc[m][n][r] + bb[n];
      }
    }
  }
}

extern "C" void kernel_launch(void* const* d_in, const int* in_sizes, int n_in,
                              void* d_out, int out_size, void* d_ws, size_t ws_size,
                              hipStream_t stream) {
  const float* x      = (const float*)d_in[0];
  const float* w_qkv  = (const float*)d_in[1];
  const float* w_proj = (const float*)d_in[2];
  const float* b_proj = (const float*)d_in[3];
  const float* rpb    = (const float*)d_in[4];
  const int*   relidx = (const int*)d_in[5];
  float* out = (float*)d_out;

  char* ws = (char*)d_ws;
  const size_t HB = (size_t)12608 * 768 * 2;  // 19,365,888 B (also per-tensor head bytes)
  ushort* xbf   = (ushort*)(ws);              // aliased by aout after qkv is consumed
  ushort* qws   = (ushort*)(ws + HB);
  ushort* kws   = (ushort*)(ws + 2 * HB);
  ushort* vws   = (ushort*)(ws + 3 * HB);
  float*  bias  = (float*)(ws + 4 * HB);                       // 2,076,672 B
  ushort* wqkvb = (ushort*)(ws + 4 * HB + 2076672);            // 3,538,944 B
  ushort* wprjb = (ushort*)(ws + 4 * HB + 2076672 + 3538944);  // 1,179,648 B
  ushort* aout  = xbf;

  hipLaunchKernelGGL(prep_bias, dim3((12 * 208 * 208 + 255) / 256), dim3(256), 0, stream,
                     rpb, relidx, bias);
  hipLaunchKernelGGL(cvt_bf16, dim3((12608 * 768 / 8 + 255) / 256), dim3(256), 0, stream,
                     x, xbf, 12608 * 768 / 8);
  hipLaunchKernelGGL(cvt_bf16, dim3((2304 * 768 / 8 + 255) / 256), dim3(256), 0, stream,
                     w_qkv, wqkvb, 2304 * 768 / 8);
  hipLaunchKernelGGL(cvt_bf16, dim3((768 * 768 / 8 + 255) / 256), dim3(256), 0, stream,
                     w_proj, wprjb, 768 * 768 / 8);
  hipLaunchKernelGGL(qkv_gemm, dim3(18, 99), dim3(256), 0, stream, xbf, wqkvb, qws, kws, vws);
  hipLaunchKernelGGL(attn, dim3(768), dim3(512), 0, stream, qws, kws, vws, bias, aout);
  hipLaunchKernelGGL(proj_gemm, dim3(6, 99), dim3(256), 0, stream, aout, wprjb, b_proj, out);
}

// Round 3
// 172.126 us; speedup vs baseline: 1.0608x; 1.0556x over previous
//
#include <hip/hip_runtime.h>

typedef float f32x4 __attribute__((ext_vector_type(4)));
typedef short short8 __attribute__((ext_vector_type(8)));

#define DEVI static __device__ __forceinline__

DEVI ushort f2bf(float f) {
  unsigned u = __builtin_bit_cast(unsigned, f);
  u += 0x7fffu + ((u >> 16) & 1u);
  return (ushort)(u >> 16);
}

DEVI short8 pack8(float4 a, float4 b) {
  union { ushort u[8]; short8 v; } t;
  t.u[0] = f2bf(a.x); t.u[1] = f2bf(a.y); t.u[2] = f2bf(a.z); t.u[3] = f2bf(a.w);
  t.u[4] = f2bf(b.x); t.u[5] = f2bf(b.y); t.u[6] = f2bf(b.z); t.u[7] = f2bf(b.w);
  return t.v;
}

DEVI f32x4 MFMA16(short8 a, short8 b, f32x4 c) {
  return __builtin_amdgcn_mfma_f32_16x16x32_bf16(a, b, c, 0, 0, 0);
}

// async global->LDS DMA, 16B/lane; LDS dest is wave-uniform base (+lane*16 by HW)
DEVI void gld16(const ushort* g, ushort* l) {
  __builtin_amdgcn_global_load_lds(
      (const __attribute__((address_space(1))) unsigned int*)g,
      (__attribute__((address_space(3))) unsigned int*)l, 16, 0, 0);
}

// ---------------- fp32 -> bf16 bulk convert (8 elems/thread) ----------------
__global__ void cvt_bf16(const float* __restrict__ s, ushort* __restrict__ d, int n8) {
  int i = blockIdx.x * 256 + threadIdx.x;
  if (i >= n8) return;
  float4 a = ((const float4*)s)[i * 2];
  float4 b = ((const float4*)s)[i * 2 + 1];
  ((short8*)d)[i] = pack8(a, b);
}

// ---------------- bias precompute: bias[h][208][208] ----------------
__global__ void prep_bias(const float* __restrict__ table, const int* __restrict__ rel_idx,
                          float* __restrict__ bias) {
  int i = blockIdx.x * 256 + threadIdx.x;
  if (i >= 12 * 208 * 208) return;
  int k = i % 208;
  int t = i / 208;
  int q = t % 208;
  int h = t / 208;
  float v;
  if (k >= 197) v = -1e30f;
  else if (q == 0 || k == 0 || q >= 197) v = 0.0f;
  else v = table[rel_idx[(q - 1) * 196 + (k - 1)] * 12 + h];
  bias[i] = v;
}

// ============ 256x256 pipelined GEMM, BK=32, 4-slot LDS ring, counted vmcnt ============
// MODE 0: qkv (A=xbf [12608,768], B=wqkv [2304,768]^T, scatter bf16 q/k/v)
// MODE 1: proj (A=aout [12608,768], B=wproj [768,768]^T, +bias -> fp32 out)
template <int MODE>
__launch_bounds__(512, 2)
__global__ void gemm256(const ushort* __restrict__ A, const ushort* __restrict__ B,
                        ushort* __restrict__ q, ushort* __restrict__ k,
                        ushort* __restrict__ v,
                        const float* __restrict__ bprj, float* __restrict__ out) {
  // ring of 4 K-tiles: A-tile [256][32] bf16 (16KB), B-tile same. Total 128KB.
  __shared__ __align__(16) ushort As[4][8192];
  __shared__ __align__(16) ushort Bs[4][8192];

  const int tid = threadIdx.x;
  const int lane = tid & 63, wid = tid >> 6;
  const int wm = wid >> 2, wn = wid & 3;
  const int l15 = lane & 15, l4 = lane >> 4;
  const int bn = blockIdx.x, bm = blockIdx.y;

  // staging source pointers (per-lane); LDS row j*128 + tid/4, col16 = tid&3
  int ar0 = bm * 256 + (tid >> 2);
  int ar1 = ar0 + 128;
  if (ar0 > 12607) ar0 = 12607;
  if (ar1 > 12607) ar1 = 12607;
  const int brow = bn * 256 + (tid >> 2);  // exact fit: 2304 (qkv) / 768 (proj)
  const ushort* pa0 = A + (size_t)ar0 * 768 + (tid & 3) * 8;
  const ushort* pa1 = A + (size_t)ar1 * 768 + (tid & 3) * 8;
  const ushort* pb0 = B + (size_t)brow * 768 + (tid & 3) * 8;
  const ushort* pb1 = B + (size_t)(brow + 128) * 768 + (tid & 3) * 8;

  const int aoff = (wm * 128 + l15) * 32 + l4 * 8;
  const int boff = (wn * 64 + l15) * 32 + l4 * 8;

  f32x4 acc[8][4];
#pragma unroll
  for (int m = 0; m < 8; m++)
#pragma unroll
    for (int n = 0; n < 4; n++) acc[m][n] = (f32x4)0.0f;

#define STAGE4(RS, KO)                              \
  gld16(pa0 + (KO), &As[RS][wid * 512]);            \
  gld16(pa1 + (KO), &As[RS][4096 + wid * 512]);     \
  gld16(pb0 + (KO), &Bs[RS][wid * 512]);            \
  gld16(pb1 + (KO), &Bs[RS][4096 + wid * 512]);

#define COMPUTE(RS)                                                 \
  {                                                                 \
    short8 af[8], bv[4];                                            \
    _Pragma("unroll") for (int m = 0; m < 8; m++)                   \
        af[m] = *(const short8*)&As[RS][aoff + m * 512];            \
    _Pragma("unroll") for (int n = 0; n < 4; n++)                   \
        bv[n] = *(const short8*)&Bs[RS][boff + n * 512];            \
    __builtin_amdgcn_s_setprio(1);                                  \
    _Pragma("unroll") for (int m = 0; m < 8; m++)                   \
        _Pragma("unroll") for (int n = 0; n < 4; n++)               \
            acc[m][n] = MFMA16(af[m], bv[n], acc[m][n]);            \
    __builtin_amdgcn_s_setprio(0);                                  \
  }

  // prologue: stages 0,1,2 in flight (12 vmcnt units; 4 per stage per wave)
  STAGE4(0, 0)
  STAGE4(1, 32)
  STAGE4(2, 64)

  // main loop: 24 K-steps total. Per iter: drain own stage-t (vmcnt 8 = keep 2
  // stages in flight), drain own ds_reads (lgkm), barrier (=> ALL waves' stage-t
  // landed; all reads of ring[t-1] consumed), then overwrite ring[t-1] with
  // stage t+3, then compute from ring[t]. Never vmcnt(0) in main loop.
  for (int t = 0; t < 21; ++t) {
    asm volatile("s_waitcnt vmcnt(8)" ::: "memory");
    asm volatile("s_waitcnt lgkmcnt(0)" ::: "memory");
    __builtin_amdgcn_s_barrier();
    const int rs = (t + 3) & 3;
    const int ko = (t + 3) * 32;
    STAGE4(rs, ko)
    COMPUTE(t & 3)
  }
  // tails: t = 21, 22, 23 (no staging)
  asm volatile("s_waitcnt vmcnt(8)" ::: "memory");
  asm volatile("s_waitcnt lgkmcnt(0)" ::: "memory");
  __builtin_amdgcn_s_barrier();
  COMPUTE(1)
  asm volatile("s_waitcnt vmcnt(4)" ::: "memory");
  asm volatile("s_waitcnt lgkmcnt(0)" ::: "memory");
  __builtin_amdgcn_s_barrier();
  COMPUTE(2)
  asm volatile("s_waitcnt vmcnt(0)" ::: "memory");
  asm volatile("s_waitcnt lgkmcnt(0)" ::: "memory");
  __builtin_amdgcn_s_barrier();
  COMPUTE(3)

  // ---------------- epilogue ----------------
  if (MODE == 0) {
    const int s = bn / 3;  // 3 N-tiles of 256 per q/k/v section (768 each)
    ushort* dst = (s == 0) ? q : ((s == 1) ? k : v);
    const float qs = (s == 0) ? 0.125f : 1.0f;
    const int cbase = bn * 256 + wn * 64 - s * 768;  // multiple of 64
    const int hh = cbase >> 6;                       // head, uniform per wave
#pragma unroll
    for (int m = 0; m < 8; m++) {
#pragma unroll
      for (int r = 0; r < 4; r++) {
        int gm = bm * 256 + wm * 128 + m * 16 + l4 * 4 + r;
        if (gm >= 12608) continue;
        int b = gm / 197;
        int ns = gm - b * 197;
        size_t base = (size_t)((b * 12 + hh) * 197 + ns) * 64;
#pragma unroll
        for (int n = 0; n < 4; n++)
          dst[base + n * 16 + l15] = f2bf(acc[m][n][r] * qs);
      }
    }
  } else {
    float bb[4];
#pragma unroll
    for (int n = 0; n < 4; n++) bb[n] = bprj[bn * 256 + wn * 64 + n * 16 + l15];
#pragma unroll
    for (int m = 0; m < 8; m++) {
#pragma unroll
      for (int r = 0; r < 4; r++) {
        int gm = bm * 256 + wm * 128 + m * 16 + l4 * 4 + r;
        if (gm >= 12608) continue;
#pragma unroll
        for (int n = 0; n < 4; n++)
          out[(size_t)gm * 768 + bn * 256 + wn * 64 + n * 16 + l15] = acc[m][n][r] + bb[n];
      }
    }
  }
#undef STAGE4
#undef COMPUTE
}

// ---------------- fused attention per (b,h) ----------------
__launch_bounds__(512)
__global__ void attn(const ushort* __restrict__ qws, const ushort* __restrict__ kws,
                     const ushort* __restrict__ vws, const float* __restrict__ biasws,
                     ushort* __restrict__ aout) {
  __shared__ __align__(16) ushort Ks[208 * 72];
  __shared__ __align__(16) ushort Vt[64 * 232];
  __shared__ __align__(16) ushort Ps[8 * 16 * 232];

  const int bh = blockIdx.x;
  const int b = bh / 12;
  const int h = bh - b * 12;
  const ushort* qb = qws + (size_t)bh * 197 * 64;
  const ushort* kb = kws + (size_t)bh * 197 * 64;
  const ushort* vb = vws + (size_t)bh * 197 * 64;

  const int tid = threadIdx.x;
  const int lane = tid & 63, wid = tid >> 6;
  const int l15 = lane & 15, l4 = lane >> 4;

  for (int c = tid; c < 208 * 8; c += 512) {
    int n = c >> 3, col = (c & 7) << 3;
    short8 v = (short8)0;
    if (n < 197) v = *(const short8*)(kb + n * 64 + col);
    *(short8*)&Ks[n * 72 + col] = v;
  }
  for (int c = tid; c < 224 * 8; c += 512) {
    int n = c % 224;
    int d0 = (c / 224) << 3;
    ushort tmp[8] = {0, 0, 0, 0, 0, 0, 0, 0};
    if (n < 197) {
      short8 v = *(const short8*)(vb + n * 64 + d0);
#pragma unroll
      for (int j = 0; j < 8; j++) tmp[j] = (ushort)v[j];
    }
#pragma unroll
    for (int j = 0; j < 8; j++) Vt[(d0 + j) * 232 + n] = tmp[j];
  }
  __syncthreads();

  ushort* pb = &Ps[wid * (16 * 232)];
  const float* biasb = biasws + (size_t)h * 208 * 208;

  for (int t = wid; t < 13; t += 8) {
    const int q0 = t * 16;
    int qr = q0 + l15; if (qr > 196) qr = 196;
    short8 aq0 = *(const short8*)(qb + qr * 64 + (l4 << 3));
    short8 aq1 = *(const short8*)(qb + qr * 64 + 32 + (l4 << 3));

    f32x4 sc[13];
    __builtin_amdgcn_s_setprio(1);
#pragma unroll
    for (int ct = 0; ct < 13; ct++) {
      short8 b0 = *(const short8*)&Ks[(ct * 16 + l15) * 72 + (l4 << 3)];
      short8 b1 = *(const short8*)&Ks[(ct * 16 + l15) * 72 + 32 + (l4 << 3)];
      f32x4 s = (f32x4)0.0f;
      s = MFMA16(aq0, b0, s);
      s = MFMA16(aq1, b1, s);
      sc[ct] = s;
    }
    __builtin_amdgcn_s_setprio(0);

    float mx[4] = {-1e38f, -1e38f, -1e38f, -1e38f};
#pragma unroll
    for (int ct = 0; ct < 13; ct++) {
#pragma unroll
      for (int r = 0; r < 4; r++) {
        float bv = biasb[(q0 + l4 * 4 + r) * 208 + ct * 16 + l15];
        float v = sc[ct][r] + bv;
        sc[ct][r] = v;
        mx[r] = fmaxf(mx[r], v);
      }
    }
#pragma unroll
    for (int r = 0; r < 4; r++) {
      mx[r] = fmaxf(mx[r], __shfl_xor(mx[r], 1));
      mx[r] = fmaxf(mx[r], __shfl_xor(mx[r], 2));
      mx[r] = fmaxf(mx[r], __shfl_xor(mx[r], 4));
      mx[r] = fmaxf(mx[r], __shfl_xor(mx[r], 8));
    }
    float sum[4] = {0.f, 0.f, 0.f, 0.f};
#pragma unroll
    for (int ct = 0; ct < 13; ct++) {
#pragma unroll
      for (int r = 0; r < 4; r++) {
        float p = __expf(sc[ct][r] - mx[r]);
        sc[ct][r] = p;
        sum[r] += p;
      }
    }
#pragma unroll
    for (int r = 0; r < 4; r++) {
      sum[r] += __shfl_xor(sum[r], 1);
      sum[r] += __shfl_xor(sum[r], 2);
      sum[r] += __shfl_xor(sum[r], 4);
      sum[r] += __shfl_xor(sum[r], 8);
    }

#pragma unroll
    for (int ct = 0; ct < 13; ct++)
#pragma unroll
      for (int r = 0; r < 4; r++)
        pb[(l4 * 4 + r) * 232 + ct * 16 + l15] = f2bf(sc[ct][r]);
#pragma unroll
    for (int r = 0; r < 4; r++)
      pb[(l4 * 4 + r) * 232 + 208 + l15] = 0;

    short8 pa[7];
#pragma unroll
    for (int kk = 0; kk < 7; kk++)
      pa[kk] = *(const short8*)&pb[l15 * 232 + kk * 32 + (l4 << 3)];
    f32x4 o[4];
    __builtin_amdgcn_s_setprio(1);
#pragma unroll
    for (int dt = 0; dt < 4; dt++) {
      f32x4 acc = (f32x4)0.0f;
#pragma unroll
      for (int kk = 0; kk < 7; kk++) {
        short8 bv = *(const short8*)&Vt[(dt * 16 + l15) * 232 + kk * 32 + (l4 << 3)];
        acc = MFMA16(pa[kk], bv, acc);
      }
      o[dt] = acc;
    }
    __builtin_amdgcn_s_setprio(0);

    float rs[4];
#pragma unroll
    for (int r = 0; r < 4; r++) rs[r] = 1.0f / sum[r];
#pragma unroll
    for (int dt = 0; dt < 4; dt++) {
#pragma unroll
      for (int r = 0; r < 4; r++) {
        int row = q0 + l4 * 4 + r;
        if (row < 197) {
          float v = o[dt][r] * rs[r];
          aout[(size_t)(b * 197 + row) * 768 + h * 64 + dt * 16 + l15] = f2bf(v);
        }
      }
    }
  }
}

extern "C" void kernel_launch(void* const* d_in, const int* in_sizes, int n_in,
                              void* d_out, int out_size, void* d_ws, size_t ws_size,
                              hipStream_t stream) {
  const float* x      = (const float*)d_in[0];
  const float* w_qkv  = (const float*)d_in[1];
  const float* w_proj = (const float*)d_in[2];
  const float* b_proj = (const float*)d_in[3];
  const float* rpb    = (const float*)d_in[4];
  const int*   relidx = (const int*)d_in[5];
  float* out = (float*)d_out;

  char* ws = (char*)d_ws;
  const size_t HB = (size_t)12608 * 768 * 2;  // 19,365,888 B
  ushort* xbf   = (ushort*)(ws);              // aliased by aout after qkv is consumed
  ushort* qws   = (ushort*)(ws + HB);
  ushort* kws   = (ushort*)(ws + 2 * HB);
  ushort* vws   = (ushort*)(ws + 3 * HB);
  float*  bias  = (float*)(ws + 4 * HB);                       // 2,076,672 B
  ushort* wqkvb = (ushort*)(ws + 4 * HB + 2076672);            // 3,538,944 B
  ushort* wprjb = (ushort*)(ws + 4 * HB + 2076672 + 3538944);  // 1,179,648 B
  ushort* aout  = xbf;

  hipLaunchKernelGGL(prep_bias, dim3((12 * 208 * 208 + 255) / 256), dim3(256), 0, stream,
                     rpb, relidx, bias);
  hipLaunchKernelGGL(cvt_bf16, dim3((12608 * 768 / 8 + 255) / 256), dim3(256), 0, stream,
                     x, xbf, 12608 * 768 / 8);
  hipLaunchKernelGGL(cvt_bf16, dim3((2304 * 768 / 8 + 255) / 256), dim3(256), 0, stream,
                     w_qkv, wqkvb, 2304 * 768 / 8);
  hipLaunchKernelGGL(cvt_bf16, dim3((768 * 768 / 8 + 255) / 256), dim3(256), 0, stream,
                     w_proj, wprjb, 768 * 768 / 8);
  hipLaunchKernelGGL((gemm256<0>), dim3(9, 50), dim3(512), 0, stream,
                     xbf, wqkvb, qws, kws, vws, nullptr, nullptr);
  hipLaunchKernelGGL(attn, dim3(768), dim3(512), 0, stream, qws, kws, vws, bias, aout);
  hipLaunchKernelGGL((gemm256<1>), dim3(3, 50), dim3(512), 0, stream,
                     aout, wprjb, nullptr, nullptr, nullptr, b_proj, out);
}

// Round 4
// 145.668 us; speedup vs baseline: 1.2535x; 1.1816x over previous
//
#include <hip/hip_runtime.h>

typedef float f32x4 __attribute__((ext_vector_type(4)));
typedef short short8 __attribute__((ext_vector_type(8)));

#define DEVI static __device__ __forceinline__

DEVI ushort f2bf(float f) {
  unsigned u = __builtin_bit_cast(unsigned, f);
  u += 0x7fffu + ((u >> 16) & 1u);
  return (ushort)(u >> 16);
}

DEVI short8 pack8(float4 a, float4 b) {
  union { ushort u[8]; short8 v; } t;
  t.u[0] = f2bf(a.x); t.u[1] = f2bf(a.y); t.u[2] = f2bf(a.z); t.u[3] = f2bf(a.w);
  t.u[4] = f2bf(b.x); t.u[5] = f2bf(b.y); t.u[6] = f2bf(b.z); t.u[7] = f2bf(b.w);
  return t.v;
}

DEVI f32x4 MFMA16(short8 a, short8 b, f32x4 c) {
  return __builtin_amdgcn_mfma_f32_16x16x32_bf16(a, b, c, 0, 0, 0);
}

// async global->LDS DMA, 16B/lane; LDS dest is wave-uniform base (+lane*16 by HW)
DEVI void gld16(const ushort* g, ushort* l) {
  __builtin_amdgcn_global_load_lds(
      (const __attribute__((address_space(1))) unsigned int*)g,
      (__attribute__((address_space(3))) unsigned int*)l, 16, 0, 0);
}

// ---------------- fp32 -> bf16 bulk convert (8 elems/thread) ----------------
__global__ void cvt_bf16(const float* __restrict__ s, ushort* __restrict__ d, int n8) {
  int i = blockIdx.x * 256 + threadIdx.x;
  if (i >= n8) return;
  float4 a = ((const float4*)s)[i * 2];
  float4 b = ((const float4*)s)[i * 2 + 1];
  ((short8*)d)[i] = pack8(a, b);
}

// ---------------- bias precompute: bias[h][208][208] ----------------
__global__ void prep_bias(const float* __restrict__ table, const int* __restrict__ rel_idx,
                          float* __restrict__ bias) {
  int i = blockIdx.x * 256 + threadIdx.x;
  if (i >= 12 * 208 * 208) return;
  int k = i % 208;
  int t = i / 208;
  int q = t % 208;
  int h = t / 208;
  float v;
  if (k >= 197) v = -1e30f;
  else if (q == 0 || k == 0 || q >= 197) v = 0.0f;
  else v = table[rel_idx[(q - 1) * 196 + (k - 1)] * 12 + h];
  bias[i] = v;
}

// ====== 128x128 GEMM, BK=32, double-buffered LDS (32KB) -> 4 blocks/CU ======
// T2 swizzle both-sides: LDS linear dest, global source col ^= ((row&6)<<3) bytes,
// read addr elem-offset l4*8 ^ ((l15&6)<<2). XCD-bijective bid swizzle (m204).
// MODE 0: qkv (A=xbf [12608,768], B=wqkv [2304,768]^T, scatter bf16 q/k/v)
// MODE 1: proj (A=aout [12608,768], B=wproj [768,768]^T, +bias -> fp32 out)
template <int MODE, int NBN>
__launch_bounds__(256, 4)
__global__ void gemm128(const ushort* __restrict__ A, const ushort* __restrict__ B,
                        ushort* __restrict__ q, ushort* __restrict__ k,
                        ushort* __restrict__ v,
                        const float* __restrict__ bprj, float* __restrict__ out) {
  __shared__ __align__(16) ushort As[2][4096];  // [128][32] per buf
  __shared__ __align__(16) ushort Bs[2][4096];

  const int tid = threadIdx.x;
  const int lane = tid & 63, wid = tid >> 6;
  const int wm = wid >> 1, wn = wid & 1;
  const int l15 = lane & 15, l4 = lane >> 4;

  // bijective XCD swizzle: same-XCD blocks get a contiguous wgid chunk
  const int nwg = gridDim.x;
  const int qc = nwg >> 3, rc = nwg & 7;
  const int xcd = blockIdx.x & 7, sub = blockIdx.x >> 3;
  const int wgid = (xcd < rc ? xcd * (qc + 1) : rc * (qc + 1) + (xcd - rc) * qc) + sub;
  const int bn = wgid % NBN, bm = wgid / NBN;

  // staging: per buf, A-tile 128x32 (8KB) = 8 chunks of 1KB; wave stages chunks 2w,2w+1
  const int c0 = wid * 2, c1 = wid * 2 + 1;
  const int r0 = c0 * 16 + (lane >> 2);
  const int r1 = c1 * 16 + (lane >> 2);
  const int g = lane & 3;
  const int col0 = (g << 3) ^ ((r0 & 6) << 2);  // pre-swizzled source col (elems)
  const int col1 = (g << 3) ^ ((r1 & 6) << 2);
  long ar0 = bm * 128 + r0; if (ar0 > 12607) ar0 = 12607;
  long ar1 = bm * 128 + r1; if (ar1 > 12607) ar1 = 12607;
  const ushort* pA0 = A + ar0 * 768 + col0;
  const ushort* pA1 = A + ar1 * 768 + col1;
  const ushort* pB0 = B + (size_t)(bn * 128 + r0) * 768 + col0;
  const ushort* pB1 = B + (size_t)(bn * 128 + r1) * 768 + col1;

  // swizzled fragment-read offsets (elems); 2-way conflict max
  const int xk = (l4 * 8) ^ ((l15 & 6) << 2);
  int aoff[4], boff[4];
#pragma unroll
  for (int m = 0; m < 4; m++) aoff[m] = (wm * 64 + m * 16 + l15) * 32 + xk;
#pragma unroll
  for (int n = 0; n < 4; n++) boff[n] = (wn * 64 + n * 16 + l15) * 32 + xk;

  f32x4 acc[4][4];
#pragma unroll
  for (int m = 0; m < 4; m++)
#pragma unroll
    for (int n = 0; n < 4; n++) acc[m][n] = (f32x4)0.0f;

#define STAGE(BUF, KO)                          \
  gld16(pA0 + (KO), &As[BUF][c0 * 512]);        \
  gld16(pA1 + (KO), &As[BUF][c1 * 512]);        \
  gld16(pB0 + (KO), &Bs[BUF][c0 * 512]);        \
  gld16(pB1 + (KO), &Bs[BUF][c1 * 512]);

#define COMPUTE(BUF)                                                \
  {                                                                 \
    short8 af[4], bv[4];                                            \
    _Pragma("unroll") for (int m = 0; m < 4; m++)                   \
        af[m] = *(const short8*)&As[BUF][aoff[m]];                  \
    _Pragma("unroll") for (int n = 0; n < 4; n++)                   \
        bv[n] = *(const short8*)&Bs[BUF][boff[n]];                  \
    __builtin_amdgcn_s_setprio(1);                                  \
    _Pragma("unroll") for (int m = 0; m < 4; m++)                   \
        _Pragma("unroll") for (int n = 0; n < 4; n++)               \
            acc[m][n] = MFMA16(af[m], bv[n], acc[m][n]);            \
    __builtin_amdgcn_s_setprio(0);                                  \
  }

  STAGE(0, 0)
  // ledger: at top of iter t, only stage-t loads are outstanding (issued last
  // iter, a full COMPUTE ago) -> vmcnt(0) is cheap; lgkm(0) before barrier
  // guarantees my reads of buf[~cur] finished before anyone overwrites it.
  for (int t = 0; t < 23; ++t) {
    asm volatile("s_waitcnt vmcnt(0) lgkmcnt(0)" ::: "memory");
    __builtin_amdgcn_s_barrier();
    __builtin_amdgcn_sched_barrier(0);
    STAGE((t + 1) & 1, (t + 1) * 32)
    COMPUTE(t & 1)
  }
  asm volatile("s_waitcnt vmcnt(0) lgkmcnt(0)" ::: "memory");
  __builtin_amdgcn_s_barrier();
  __builtin_amdgcn_sched_barrier(0);
  COMPUTE(1)

  // ---------------- epilogue ----------------
  if (MODE == 0) {
    const int s = bn / 6;
    ushort* dst = (s == 0) ? q : ((s == 1) ? k : v);
    const float qs = (s == 0) ? 0.125f : 1.0f;
    const int cbase = bn * 128 + wn * 64 - s * 768;  // multiple of 64
    const int hh = cbase >> 6;
#pragma unroll
    for (int m = 0; m < 4; m++) {
#pragma unroll
      for (int r = 0; r < 4; r++) {
        int gm = bm * 128 + wm * 64 + m * 16 + l4 * 4 + r;
        if (gm >= 12608) continue;
        int b = gm / 197;
        int ns = gm - b * 197;
        size_t base = (size_t)((b * 12 + hh) * 197 + ns) * 64;
#pragma unroll
        for (int n = 0; n < 4; n++)
          dst[base + n * 16 + l15] = f2bf(acc[m][n][r] * qs);
      }
    }
  } else {
    float bb[4];
#pragma unroll
    for (int n = 0; n < 4; n++) bb[n] = bprj[bn * 128 + wn * 64 + n * 16 + l15];
#pragma unroll
    for (int m = 0; m < 4; m++) {
#pragma unroll
      for (int r = 0; r < 4; r++) {
        int gm = bm * 128 + wm * 64 + m * 16 + l4 * 4 + r;
        if (gm >= 12608) continue;
#pragma unroll
        for (int n = 0; n < 4; n++)
          out[(size_t)gm * 768 + bn * 128 + wn * 64 + n * 16 + l15] = acc[m][n][r] + bb[n];
      }
    }
  }
#undef STAGE
#undef COMPUTE
}

// ---------------- fused attention per (b,h) ----------------
__launch_bounds__(512)
__global__ void attn(const ushort* __restrict__ qws, const ushort* __restrict__ kws,
                     const ushort* __restrict__ vws, const float* __restrict__ biasws,
                     ushort* __restrict__ aout) {
  __shared__ __align__(16) ushort Ks[208 * 72];
  __shared__ __align__(16) ushort Vt[64 * 232];
  __shared__ __align__(16) ushort Ps[8 * 16 * 232];

  const int bh = blockIdx.x;
  const int b = bh / 12;
  const int h = bh - b * 12;
  const ushort* qb = qws + (size_t)bh * 197 * 64;
  const ushort* kb = kws + (size_t)bh * 197 * 64;
  const ushort* vb = vws + (size_t)bh * 197 * 64;

  const int tid = threadIdx.x;
  const int lane = tid & 63, wid = tid >> 6;
  const int l15 = lane & 15, l4 = lane >> 4;

  for (int c = tid; c < 208 * 8; c += 512) {
    int n = c >> 3, col = (c & 7) << 3;
    short8 v = (short8)0;
    if (n < 197) v = *(const short8*)(kb + n * 64 + col);
    *(short8*)&Ks[n * 72 + col] = v;
  }
  for (int c = tid; c < 224 * 8; c += 512) {
    int n = c % 224;
    int d0 = (c / 224) << 3;
    ushort tmp[8] = {0, 0, 0, 0, 0, 0, 0, 0};
    if (n < 197) {
      short8 v = *(const short8*)(vb + n * 64 + d0);
#pragma unroll
      for (int j = 0; j < 8; j++) tmp[j] = (ushort)v[j];
    }
#pragma unroll
    for (int j = 0; j < 8; j++) Vt[(d0 + j) * 232 + n] = tmp[j];
  }
  __syncthreads();

  ushort* pb = &Ps[wid * (16 * 232)];
  const float* biasb = biasws + (size_t)h * 208 * 208;

  for (int t = wid; t < 13; t += 8) {
    const int q0 = t * 16;
    int qr = q0 + l15; if (qr > 196) qr = 196;
    short8 aq0 = *(const short8*)(qb + qr * 64 + (l4 << 3));
    short8 aq1 = *(const short8*)(qb + qr * 64 + 32 + (l4 << 3));

    f32x4 sc[13];
    __builtin_amdgcn_s_setprio(1);
#pragma unroll
    for (int ct = 0; ct < 13; ct++) {
      short8 b0 = *(const short8*)&Ks[(ct * 16 + l15) * 72 + (l4 << 3)];
      short8 b1 = *(const short8*)&Ks[(ct * 16 + l15) * 72 + 32 + (l4 << 3)];
      f32x4 s = (f32x4)0.0f;
      s = MFMA16(aq0, b0, s);
      s = MFMA16(aq1, b1, s);
      sc[ct] = s;
    }
    __builtin_amdgcn_s_setprio(0);

    float mx[4] = {-1e38f, -1e38f, -1e38f, -1e38f};
#pragma unroll
    for (int ct = 0; ct < 13; ct++) {
#pragma unroll
      for (int r = 0; r < 4; r++) {
        float bv = biasb[(q0 + l4 * 4 + r) * 208 + ct * 16 + l15];
        float v = sc[ct][r] + bv;
        sc[ct][r] = v;
        mx[r] = fmaxf(mx[r], v);
      }
    }
#pragma unroll
    for (int r = 0; r < 4; r++) {
      mx[r] = fmaxf(mx[r], __shfl_xor(mx[r], 1));
      mx[r] = fmaxf(mx[r], __shfl_xor(mx[r], 2));
      mx[r] = fmaxf(mx[r], __shfl_xor(mx[r], 4));
      mx[r] = fmaxf(mx[r], __shfl_xor(mx[r], 8));
    }
    float sum[4] = {0.f, 0.f, 0.f, 0.f};
#pragma unroll
    for (int ct = 0; ct < 13; ct++) {
#pragma unroll
      for (int r = 0; r < 4; r++) {
        float p = __expf(sc[ct][r] - mx[r]);
        sc[ct][r] = p;
        sum[r] += p;
      }
    }
#pragma unroll
    for (int r = 0; r < 4; r++) {
      sum[r] += __shfl_xor(sum[r], 1);
      sum[r] += __shfl_xor(sum[r], 2);
      sum[r] += __shfl_xor(sum[r], 4);
      sum[r] += __shfl_xor(sum[r], 8);
    }

#pragma unroll
    for (int ct = 0; ct < 13; ct++)
#pragma unroll
      for (int r = 0; r < 4; r++)
        pb[(l4 * 4 + r) * 232 + ct * 16 + l15] = f2bf(sc[ct][r]);
#pragma unroll
    for (int r = 0; r < 4; r++)
      pb[(l4 * 4 + r) * 232 + 208 + l15] = 0;

    short8 pa[7];
#pragma unroll
    for (int kk = 0; kk < 7; kk++)
      pa[kk] = *(const short8*)&pb[l15 * 232 + kk * 32 + (l4 << 3)];
    f32x4 o[4];
    __builtin_amdgcn_s_setprio(1);
#pragma unroll
    for (int dt = 0; dt < 4; dt++) {
      f32x4 acc = (f32x4)0.0f;
#pragma unroll
      for (int kk = 0; kk < 7; kk++) {
        short8 bv = *(const short8*)&Vt[(dt * 16 + l15) * 232 + kk * 32 + (l4 << 3)];
        acc = MFMA16(pa[kk], bv, acc);
      }
      o[dt] = acc;
    }
    __builtin_amdgcn_s_setprio(0);

    float rs[4];
#pragma unroll
    for (int r = 0; r < 4; r++) rs[r] = 1.0f / sum[r];
#pragma unroll
    for (int dt = 0; dt < 4; dt++) {
#pragma unroll
      for (int r = 0; r < 4; r++) {
        int row = q0 + l4 * 4 + r;
        if (row < 197) {
          float v = o[dt][r] * rs[r];
          aout[(size_t)(b * 197 + row) * 768 + h * 64 + dt * 16 + l15] = f2bf(v);
        }
      }
    }
  }
}

extern "C" void kernel_launch(void* const* d_in, const int* in_sizes, int n_in,
                              void* d_out, int out_size, void* d_ws, size_t ws_size,
                              hipStream_t stream) {
  const float* x      = (const float*)d_in[0];
  const float* w_qkv  = (const float*)d_in[1];
  const float* w_proj = (const float*)d_in[2];
  const float* b_proj = (const float*)d_in[3];
  const float* rpb    = (const float*)d_in[4];
  const int*   relidx = (const int*)d_in[5];
  float* out = (float*)d_out;

  char* ws = (char*)d_ws;
  const size_t HB = (size_t)12608 * 768 * 2;  // 19,365,888 B
  ushort* xbf   = (ushort*)(ws);              // aliased by aout after qkv is consumed
  ushort* qws   = (ushort*)(ws + HB);
  ushort* kws   = (ushort*)(ws + 2 * HB);
  ushort* vws   = (ushort*)(ws + 3 * HB);
  float*  bias  = (float*)(ws + 4 * HB);                       // 2,076,672 B
  ushort* wqkvb = (ushort*)(ws + 4 * HB + 2076672);            // 3,538,944 B
  ushort* wprjb = (ushort*)(ws + 4 * HB + 2076672 + 3538944);  // 1,179,648 B
  ushort* aout  = xbf;

  hipLaunchKernelGGL(prep_bias, dim3((12 * 208 * 208 + 255) / 256), dim3(256), 0, stream,
                     rpb, relidx, bias);
  hipLaunchKernelGGL(cvt_bf16, dim3((12608 * 768 / 8 + 255) / 256), dim3(256), 0, stream,
                     x, xbf, 12608 * 768 / 8);
  hipLaunchKernelGGL(cvt_bf16, dim3((2304 * 768 / 8 + 255) / 256), dim3(256), 0, stream,
                     w_qkv, wqkvb, 2304 * 768 / 8);
  hipLaunchKernelGGL(cvt_bf16, dim3((768 * 768 / 8 + 255) / 256), dim3(256), 0, stream,
                     w_proj, wprjb, 768 * 768 / 8);
  hipLaunchKernelGGL((gemm128<0, 18>), dim3(18 * 99), dim3(256), 0, stream,
                     xbf, wqkvb, qws, kws, vws, nullptr, nullptr);
  hipLaunchKernelGGL(attn, dim3(768), dim3(512), 0, stream, qws, kws, vws, bias, aout);
  hipLaunchKernelGGL((gemm128<1, 6>), dim3(6 * 99), dim3(256), 0, stream,
                     aout, wprjb, nullptr, nullptr, nullptr, b_proj, out);
}

// Round 5
// 145.072 us; speedup vs baseline: 1.2587x; 1.0041x over previous
//
#include <hip/hip_runtime.h>

typedef float f32x4 __attribute__((ext_vector_type(4)));
typedef short short8 __attribute__((ext_vector_type(8)));

#define DEVI static __device__ __forceinline__

DEVI ushort f2bf(float f) {
  unsigned u = __builtin_bit_cast(unsigned, f);
  u += 0x7fffu + ((u >> 16) & 1u);
  return (ushort)(u >> 16);
}

DEVI short8 pack8(float4 a, float4 b) {
  union { ushort u[8]; short8 v; } t;
  t.u[0] = f2bf(a.x); t.u[1] = f2bf(a.y); t.u[2] = f2bf(a.z); t.u[3] = f2bf(a.w);
  t.u[4] = f2bf(b.x); t.u[5] = f2bf(b.y); t.u[6] = f2bf(b.z); t.u[7] = f2bf(b.w);
  return t.v;
}

DEVI f32x4 MFMA16(short8 a, short8 b, f32x4 c) {
  return __builtin_amdgcn_mfma_f32_16x16x32_bf16(a, b, c, 0, 0, 0);
}

// async global->LDS DMA, 16B/lane; LDS dest is wave-uniform base (+lane*16 by HW)
DEVI void gld16(const ushort* g, ushort* l) {
  __builtin_amdgcn_global_load_lds(
      (const __attribute__((address_space(1))) unsigned int*)g,
      (__attribute__((address_space(3))) unsigned int*)l, 16, 0, 0);
}

// ---------------- fused prep: bias materialize + 3 bf16 converts ----------------
// block ranges (all exact multiples of 256 elems):
//   [0,2028)        bias   12*208*208 = 519168
//   [2028,6756)     cvt x  12608*768/8 = 1210368 (8-elem items)
//   [6756,7620)     cvt w_qkv 2304*768/8 = 221184
//   [7620,7908)     cvt w_proj 768*768/8 = 73728
__global__ void prep_all(const float* __restrict__ table, const int* __restrict__ rel_idx,
                         float* __restrict__ bias,
                         const float* __restrict__ x, ushort* __restrict__ xbf,
                         const float* __restrict__ wq, ushort* __restrict__ wqb,
                         const float* __restrict__ wp, ushort* __restrict__ wpb) {
  const int bid = blockIdx.x, tid = threadIdx.x;
  if (bid < 2028) {
    int i = bid * 256 + tid;
    int k = i % 208;
    int t = i / 208;
    int q = t % 208;
    int h = t / 208;
    float v;
    if (k >= 197) v = -1e30f;
    else if (q == 0 || k == 0 || q >= 197) v = 0.0f;
    else v = table[rel_idx[(q - 1) * 196 + (k - 1)] * 12 + h];
    bias[i] = v;
  } else if (bid < 6756) {
    int i = (bid - 2028) * 256 + tid;
    float4 a = ((const float4*)x)[i * 2];
    float4 b = ((const float4*)x)[i * 2 + 1];
    ((short8*)xbf)[i] = pack8(a, b);
  } else if (bid < 7620) {
    int i = (bid - 6756) * 256 + tid;
    float4 a = ((const float4*)wq)[i * 2];
    float4 b = ((const float4*)wq)[i * 2 + 1];
    ((short8*)wqb)[i] = pack8(a, b);
  } else {
    int i = (bid - 7620) * 256 + tid;
    float4 a = ((const float4*)wp)[i * 2];
    float4 b = ((const float4*)wp)[i * 2 + 1];
    ((short8*)wpb)[i] = pack8(a, b);
  }
}

// ====== 128x128 GEMM, BK=32, 3-slot LDS ring (48KB), counted vmcnt(4) ======
// depth-2 prefetch: stages t and t+1 in flight across each barrier; never
// drain to 0 in the main loop (T4). T2 swizzle both-sides; XCD-bijective bid
// swizzle (m204). 3 blocks/CU.
// MODE 0: qkv (A=xbf [12608,768], B=wqkv [2304,768]^T, scatter bf16 q/k/v)
// MODE 1: proj (A=aout [12608,768], B=wproj [768,768]^T, +bias -> fp32 out)
template <int MODE, int NBN>
__launch_bounds__(256, 3)
__global__ void gemm128(const ushort* __restrict__ A, const ushort* __restrict__ B,
                        ushort* __restrict__ q, ushort* __restrict__ k,
                        ushort* __restrict__ v,
                        const float* __restrict__ bprj, float* __restrict__ out) {
  __shared__ __align__(16) ushort As[3][4096];  // [128][32] per slot
  __shared__ __align__(16) ushort Bs[3][4096];

  const int tid = threadIdx.x;
  const int lane = tid & 63, wid = tid >> 6;
  const int wm = wid >> 1, wn = wid & 1;
  const int l15 = lane & 15, l4 = lane >> 4;

  // bijective XCD swizzle: same-XCD blocks get a contiguous wgid chunk
  const int nwg = gridDim.x;
  const int qc = nwg >> 3, rc = nwg & 7;
  const int xcd = blockIdx.x & 7, sub = blockIdx.x >> 3;
  const int wgid = (xcd < rc ? xcd * (qc + 1) : rc * (qc + 1) + (xcd - rc) * qc) + sub;
  const int bn = wgid % NBN, bm = wgid / NBN;

  // staging: per slot, A-tile 128x32 (8KB) = 8 chunks of 1KB; wave stages chunks 2w,2w+1
  const int c0 = wid * 2, c1 = wid * 2 + 1;
  const int r0 = c0 * 16 + (lane >> 2);
  const int r1 = c1 * 16 + (lane >> 2);
  const int g = lane & 3;
  const int col0 = (g << 3) ^ ((r0 & 6) << 2);  // pre-swizzled source col (elems)
  const int col1 = (g << 3) ^ ((r1 & 6) << 2);
  long ar0 = bm * 128 + r0; if (ar0 > 12607) ar0 = 12607;
  long ar1 = bm * 128 + r1; if (ar1 > 12607) ar1 = 12607;
  const ushort* pA0 = A + ar0 * 768 + col0;
  const ushort* pA1 = A + ar1 * 768 + col1;
  const ushort* pB0 = B + (size_t)(bn * 128 + r0) * 768 + col0;
  const ushort* pB1 = B + (size_t)(bn * 128 + r1) * 768 + col1;

  // swizzled fragment-read offsets (elems); 2-way conflict max
  const int xk = (l4 * 8) ^ ((l15 & 6) << 2);
  int aoff[4], boff[4];
#pragma unroll
  for (int m = 0; m < 4; m++) aoff[m] = (wm * 64 + m * 16 + l15) * 32 + xk;
#pragma unroll
  for (int n = 0; n < 4; n++) boff[n] = (wn * 64 + n * 16 + l15) * 32 + xk;

  f32x4 acc[4][4];
#pragma unroll
  for (int m = 0; m < 4; m++)
#pragma unroll
    for (int n = 0; n < 4; n++) acc[m][n] = (f32x4)0.0f;

#define STAGE(SL, KO)                           \
  gld16(pA0 + (KO), &As[SL][c0 * 512]);         \
  gld16(pA1 + (KO), &As[SL][c1 * 512]);         \
  gld16(pB0 + (KO), &Bs[SL][c0 * 512]);         \
  gld16(pB1 + (KO), &Bs[SL][c1 * 512]);

#define COMPUTE(SL)                                                 \
  {                                                                 \
    short8 af[4], bv[4];                                            \
    _Pragma("unroll") for (int m = 0; m < 4; m++)                   \
        af[m] = *(const short8*)&As[SL][aoff[m]];                   \
    _Pragma("unroll") for (int n = 0; n < 4; n++)                   \
        bv[n] = *(const short8*)&Bs[SL][boff[n]];                   \
    __builtin_amdgcn_s_setprio(1);                                  \
    _Pragma("unroll") for (int m = 0; m < 4; m++)                   \
        _Pragma("unroll") for (int n = 0; n < 4; n++)               \
            acc[m][n] = MFMA16(af[m], bv[n], acc[m][n]);            \
    __builtin_amdgcn_s_setprio(0);                                  \
  }

  // prologue: stages 0 and 1 in flight (8 vmem ops/wave)
  STAGE(0, 0)
  STAGE(1, 32)

  // ledger (24 K-steps): at top of iter t, outstanding = stages t, t+1 (8 ops).
  // vmcnt(4) drains stage t only (stage t+1 rides across the barrier). After
  // the barrier every wave's stage-t has landed (RAW ok). STAGE(t+2) then
  // overwrites slot(t-1), whose reads finished before each wave's lgkm(0)
  // at this barrier (WAR ok). Lookahead = 2 compute-phases.
  int sl_c = 0, sl_s = 2;
  for (int t = 0; t < 22; ++t) {
    asm volatile("s_waitcnt vmcnt(4)" ::: "memory");
    asm volatile("s_waitcnt lgkmcnt(0)" ::: "memory");
    __builtin_amdgcn_s_barrier();
    __builtin_amdgcn_sched_barrier(0);
    STAGE(sl_s, (t + 2) * 32)
    COMPUTE(sl_c)
    sl_c = (sl_c == 2) ? 0 : sl_c + 1;
    sl_s = (sl_s == 2) ? 0 : sl_s + 1;
  }
  // t=22: outstanding = stages 22,23 -> vmcnt(4) drains 22
  asm volatile("s_waitcnt vmcnt(4)" ::: "memory");
  asm volatile("s_waitcnt lgkmcnt(0)" ::: "memory");
  __builtin_amdgcn_s_barrier();
  __builtin_amdgcn_sched_barrier(0);
  COMPUTE(1)
  // t=23: only stage 23 outstanding -> must drain to 0
  asm volatile("s_waitcnt vmcnt(0)" ::: "memory");
  asm volatile("s_waitcnt lgkmcnt(0)" ::: "memory");
  __builtin_amdgcn_s_barrier();
  __builtin_amdgcn_sched_barrier(0);
  COMPUTE(2)

  // ---------------- epilogue ----------------
  if (MODE == 0) {
    const int s = bn / 6;
    ushort* dst = (s == 0) ? q : ((s == 1) ? k : v);
    const float qs = (s == 0) ? 0.125f : 1.0f;
    const int cbase = bn * 128 + wn * 64 - s * 768;  // multiple of 64
    const int hh = cbase >> 6;
#pragma unroll
    for (int m = 0; m < 4; m++) {
#pragma unroll
      for (int r = 0; r < 4; r++) {
        int gm = bm * 128 + wm * 64 + m * 16 + l4 * 4 + r;
        if (gm >= 12608) continue;
        int b = gm / 197;
        int ns = gm - b * 197;
        size_t base = (size_t)((b * 12 + hh) * 197 + ns) * 64;
#pragma unroll
        for (int n = 0; n < 4; n++)
          dst[base + n * 16 + l15] = f2bf(acc[m][n][r] * qs);
      }
    }
  } else {
    float bb[4];
#pragma unroll
    for (int n = 0; n < 4; n++) bb[n] = bprj[bn * 128 + wn * 64 + n * 16 + l15];
#pragma unroll
    for (int m = 0; m < 4; m++) {
#pragma unroll
      for (int r = 0; r < 4; r++) {
        int gm = bm * 128 + wm * 64 + m * 16 + l4 * 4 + r;
        if (gm >= 12608) continue;
#pragma unroll
        for (int n = 0; n < 4; n++)
          out[(size_t)gm * 768 + bn * 128 + wn * 64 + n * 16 + l15] = acc[m][n][r] + bb[n];
      }
    }
  }
#undef STAGE
#undef COMPUTE
}

// ---------------- fused attention per (b,h) ----------------
__launch_bounds__(512)
__global__ void attn(const ushort* __restrict__ qws, const ushort* __restrict__ kws,
                     const ushort* __restrict__ vws, const float* __restrict__ biasws,
                     ushort* __restrict__ aout) {
  __shared__ __align__(16) ushort Ks[208 * 72];
  __shared__ __align__(16) ushort Vt[64 * 232];
  __shared__ __align__(16) ushort Ps[8 * 16 * 232];

  const int bh = blockIdx.x;
  const int b = bh / 12;
  const int h = bh - b * 12;
  const ushort* qb = qws + (size_t)bh * 197 * 64;
  const ushort* kb = kws + (size_t)bh * 197 * 64;
  const ushort* vb = vws + (size_t)bh * 197 * 64;

  const int tid = threadIdx.x;
  const int lane = tid & 63, wid = tid >> 6;
  const int l15 = lane & 15, l4 = lane >> 4;

  for (int c = tid; c < 208 * 8; c += 512) {
    int n = c >> 3, col = (c & 7) << 3;
    short8 v = (short8)0;
    if (n < 197) v = *(const short8*)(kb + n * 64 + col);
    *(short8*)&Ks[n * 72 + col] = v;
  }
  for (int c = tid; c < 224 * 8; c += 512) {
    int n = c % 224;
    int d0 = (c / 224) << 3;
    ushort tmp[8] = {0, 0, 0, 0, 0, 0, 0, 0};
    if (n < 197) {
      short8 v = *(const short8*)(vb + n * 64 + d0);
#pragma unroll
      for (int j = 0; j < 8; j++) tmp[j] = (ushort)v[j];
    }
#pragma unroll
    for (int j = 0; j < 8; j++) Vt[(d0 + j) * 232 + n] = tmp[j];
  }
  __syncthreads();

  ushort* pb = &Ps[wid * (16 * 232)];
  const float* biasb = biasws + (size_t)h * 208 * 208;

  for (int t = wid; t < 13; t += 8) {
    const int q0 = t * 16;
    int qr = q0 + l15; if (qr > 196) qr = 196;
    short8 aq0 = *(const short8*)(qb + qr * 64 + (l4 << 3));
    short8 aq1 = *(const short8*)(qb + qr * 64 + 32 + (l4 << 3));

    f32x4 sc[13];
    __builtin_amdgcn_s_setprio(1);
#pragma unroll
    for (int ct = 0; ct < 13; ct++) {
      short8 b0 = *(const short8*)&Ks[(ct * 16 + l15) * 72 + (l4 << 3)];
      short8 b1 = *(const short8*)&Ks[(ct * 16 + l15) * 72 + 32 + (l4 << 3)];
      f32x4 s = (f32x4)0.0f;
      s = MFMA16(aq0, b0, s);
      s = MFMA16(aq1, b1, s);
      sc[ct] = s;
    }
    __builtin_amdgcn_s_setprio(0);

    float mx[4] = {-1e38f, -1e38f, -1e38f, -1e38f};
#pragma unroll
    for (int ct = 0; ct < 13; ct++) {
#pragma unroll
      for (int r = 0; r < 4; r++) {
        float bv = biasb[(q0 + l4 * 4 + r) * 208 + ct * 16 + l15];
        float v = sc[ct][r] + bv;
        sc[ct][r] = v;
        mx[r] = fmaxf(mx[r], v);
      }
    }
#pragma unroll
    for (int r = 0; r < 4; r++) {
      mx[r] = fmaxf(mx[r], __shfl_xor(mx[r], 1));
      mx[r] = fmaxf(mx[r], __shfl_xor(mx[r], 2));
      mx[r] = fmaxf(mx[r], __shfl_xor(mx[r], 4));
      mx[r] = fmaxf(mx[r], __shfl_xor(mx[r], 8));
    }
    float sum[4] = {0.f, 0.f, 0.f, 0.f};
#pragma unroll
    for (int ct = 0; ct < 13; ct++) {
#pragma unroll
      for (int r = 0; r < 4; r++) {
        float p = __expf(sc[ct][r] - mx[r]);
        sc[ct][r] = p;
        sum[r] += p;
      }
    }
#pragma unroll
    for (int r = 0; r < 4; r++) {
      sum[r] += __shfl_xor(sum[r], 1);
      sum[r] += __shfl_xor(sum[r], 2);
      sum[r] += __shfl_xor(sum[r], 4);
      sum[r] += __shfl_xor(sum[r], 8);
    }

#pragma unroll
    for (int ct = 0; ct < 13; ct++)
#pragma unroll
      for (int r = 0; r < 4; r++)
        pb[(l4 * 4 + r) * 232 + ct * 16 + l15] = f2bf(sc[ct][r]);
#pragma unroll
    for (int r = 0; r < 4; r++)
      pb[(l4 * 4 + r) * 232 + 208 + l15] = 0;

    short8 pa[7];
#pragma unroll
    for (int kk = 0; kk < 7; kk++)
      pa[kk] = *(const short8*)&pb[l15 * 232 + kk * 32 + (l4 << 3)];
    f32x4 o[4];
    __builtin_amdgcn_s_setprio(1);
#pragma unroll
    for (int dt = 0; dt < 4; dt++) {
      f32x4 acc = (f32x4)0.0f;
#pragma unroll
      for (int kk = 0; kk < 7; kk++) {
        short8 bv = *(const short8*)&Vt[(dt * 16 + l15) * 232 + kk * 32 + (l4 << 3)];
        acc = MFMA16(pa[kk], bv, acc);
      }
      o[dt] = acc;
    }
    __builtin_amdgcn_s_setprio(0);

    float rs[4];
#pragma unroll
    for (int r = 0; r < 4; r++) rs[r] = 1.0f / sum[r];
#pragma unroll
    for (int dt = 0; dt < 4; dt++) {
#pragma unroll
      for (int r = 0; r < 4; r++) {
        int row = q0 + l4 * 4 + r;
        if (row < 197) {
          float v = o[dt][r] * rs[r];
          aout[(size_t)(b * 197 + row) * 768 + h * 64 + dt * 16 + l15] = f2bf(v);
        }
      }
    }
  }
}

extern "C" void kernel_launch(void* const* d_in, const int* in_sizes, int n_in,
                              void* d_out, int out_size, void* d_ws, size_t ws_size,
                              hipStream_t stream) {
  const float* x      = (const float*)d_in[0];
  const float* w_qkv  = (const float*)d_in[1];
  const float* w_proj = (const float*)d_in[2];
  const float* b_proj = (const float*)d_in[3];
  const float* rpb    = (const float*)d_in[4];
  const int*   relidx = (const int*)d_in[5];
  float* out = (float*)d_out;

  char* ws = (char*)d_ws;
  const size_t HB = (size_t)12608 * 768 * 2;  // 19,365,888 B
  ushort* xbf   = (ushort*)(ws);              // aliased by aout after qkv is consumed
  ushort* qws   = (ushort*)(ws + HB);
  ushort* kws   = (ushort*)(ws + 2 * HB);
  ushort* vws   = (ushort*)(ws + 3 * HB);
  float*  bias  = (float*)(ws + 4 * HB);                       // 2,076,672 B
  ushort* wqkvb = (ushort*)(ws + 4 * HB + 2076672);            // 3,538,944 B
  ushort* wprjb = (ushort*)(ws + 4 * HB + 2076672 + 3538944);  // 1,179,648 B
  ushort* aout  = xbf;

  hipLaunchKernelGGL(prep_all, dim3(7908), dim3(256), 0, stream,
                     rpb, relidx, bias, x, xbf, w_qkv, wqkvb, w_proj, wprjb);
  hipLaunchKernelGGL((gemm128<0, 18>), dim3(18 * 99), dim3(256), 0, stream,
                     xbf, wqkvb, qws, kws, vws, nullptr, nullptr);
  hipLaunchKernelGGL(attn, dim3(768), dim3(512), 0, stream, qws, kws, vws, bias, aout);
  hipLaunchKernelGGL((gemm128<1, 6>), dim3(6 * 99), dim3(256), 0, stream,
                     aout, wprjb, nullptr, nullptr, nullptr, b_proj, out);
}